// Round 3
// baseline (1027.266 us; speedup 1.0000x reference)
//
#include <hip/hip_runtime.h>
#include <math.h>

#define BB 2
#define CDIM 256
#define NHEADS 8
#define HD 32
#define HH 40
#define WW 40
#define NN 1600
#define C3 768
#define SCALE 0.17677669529663687f  // 1/sqrt(32)
#define RTE 8            // rows per block, entropy kernel (2 per wave)
#define RTS 2            // rows per block, sparse kernel (1 wave)
#define TSTR 2048        // tile stride: 64 j * 32 d  (layout [kt][j][d], d contiguous)
#define HSTR 51200       // per (b,part,h): 25 tiles * 2048

typedef __attribute__((ext_vector_type(4))) float f4;

// ---------- helpers ----------
__device__ inline unsigned fkey(float f) {
    unsigned u = __float_as_uint(f);
    return (u & 0x80000000u) ? ~u : (u | 0x80000000u);
}
__device__ inline float finv(unsigned u) {
    unsigned v = (u & 0x80000000u) ? (u ^ 0x80000000u) : ~u;
    return __uint_as_float(v);
}

// ---------- 1x1 conv: 8 output channels per thread ----------
__global__ __launch_bounds__(256) void conv1x1_kernel(const float* __restrict__ x,
                                                      const float* __restrict__ w,
                                                      const float* __restrict__ bias,
                                                      float* __restrict__ out) {
    int blk = blockIdx.x;
    int st = blk % 7;
    int t2 = blk / 7;
    int ocg = t2 % (C3 / 8);
    int b = t2 / (C3 / 8);
    int s = st * 256 + threadIdx.x;
    if (s >= NN) return;
    int oc0 = ocg * 8;
    const float* xb = x + (size_t)b * CDIM * NN + s;
    const float* w0 = w + (size_t)oc0 * CDIM;
    float a[8];
#pragma unroll
    for (int i = 0; i < 8; i++) a[i] = bias[oc0 + i];
#pragma unroll 4
    for (int ic = 0; ic < CDIM; ic++) {
        float xv = xb[(size_t)ic * NN];
#pragma unroll
        for (int i = 0; i < 8; i++) a[i] += w0[i * CDIM + ic] * xv;
    }
    float* ob = out + ((size_t)b * C3 + oc0) * NN + s;
#pragma unroll
    for (int i = 0; i < 8; i++) ob[(size_t)i * NN] = a[i];
}

// ---------- depthwise 3x3 pad1; writes j-tiled layout [b][part][h][kt][j][d] ----------
__global__ __launch_bounds__(256) void dwconv_kernel(const float* __restrict__ in,
                                                     const float* __restrict__ w,
                                                     const float* __restrict__ bias,
                                                     float* __restrict__ out_t) {
    int idx = blockIdx.x * 256 + threadIdx.x;
    int s = idx % NN;
    int t = idx / NN;
    int c = t % C3;
    int b = t / C3;
    int y = s / WW, xx = s % WW;
    const float* ib = in + ((size_t)b * C3 + c) * NN;
    const float* wr = w + (size_t)c * 9;
    float acc = bias[c];
#pragma unroll
    for (int ky = 0; ky < 3; ky++) {
        int iy = y + ky - 1;
        if (iy < 0 || iy >= HH) continue;
#pragma unroll
        for (int kx = 0; kx < 3; kx++) {
            int ix = xx + kx - 1;
            if (ix < 0 || ix >= WW) continue;
            acc += wr[ky * 3 + kx] * ib[iy * WW + ix];
        }
    }
    int part = c >> 8;
    int r = c & 255;
    int hh = r >> 5;
    int d = r & 31;
    out_t[((size_t)(b * 3 + part) * NHEADS + hh) * HSTR + (s >> 6) * TSTR + (s & 63) * 32 + d] = acc;
}

// ---------- phase 1: streaming entropy on [kt][j][d] layout; f4 K loads ----------
__global__ __launch_bounds__(256) void entropy_kernel(const float* __restrict__ qkv_t,
                                                      float* __restrict__ ent) {
    int blk = blockIdx.x;      // bh*(NN/RTE) + rt
    int rt = blk % (NN / RTE);
    int bh = blk / (NN / RTE);
    int h = bh % NHEADS, b = bh / NHEADS;
    int row0 = rt * RTE;
    __shared__ float Qs[RTE][HD];
    int tid = threadIdx.x;
    const float* qt = qkv_t + ((size_t)(b * 3 + 0) * NHEADS + h) * HSTR;
    const float* ktb = qkv_t + ((size_t)(b * 3 + 1) * NHEADS + h) * HSTR;
    {
        int r = tid >> 5, d = tid & 31;
        int row = row0 + r;
        Qs[r][d] = qt[(row >> 6) * TSTR + (row & 63) * 32 + d];
    }
    __syncthreads();
    int w = tid >> 6, lane = tid & 63;
    int lr0 = 2 * w, lr1 = lr0 + 1;
    float q0[HD], q1[HD];
#pragma unroll
    for (int d = 0; d < HD; d++) { q0[d] = Qs[lr0][d]; q1[d] = Qs[lr1][d]; }
    float S0 = 0.f, T0 = 0.f, S1 = 0.f, T1 = 0.f;
#pragma unroll 1
    for (int kt = 0; kt < 25; kt++) {
        const f4* kp = (const f4*)(ktb + kt * TSTR + lane * 32);
        f4 kc[8];
#pragma unroll
        for (int i = 0; i < 8; i++) kc[i] = kp[i];
        float a0 = 0.f, a1 = 0.f;
#pragma unroll
        for (int i = 0; i < 8; i++) {
#pragma unroll
            for (int c = 0; c < 4; c++) {
                float kv = kc[i][c];
                a0 += q0[i * 4 + c] * kv;
                a1 += q1[i * 4 + c] * kv;
            }
        }
        a0 *= SCALE; a1 *= SCALE;
        float e0 = __expf(a0), e1 = __expf(a1);
        S0 += e0; T0 += e0 * a0;
        S1 += e1; T1 += e1 * a1;
    }
#pragma unroll
    for (int o = 1; o < 64; o <<= 1) {
        S0 += __shfl_xor(S0, o); T0 += __shfl_xor(T0, o);
        S1 += __shfl_xor(S1, o); T1 += __shfl_xor(T1, o);
    }
    if (lane == 0) {
        ent[(size_t)bh * NN + row0 + lr0] = logf(S0) - T0 / S0;
        ent[(size_t)bh * NN + row0 + lr1] = logf(S1) - T1 / S1;
    }
}

// ---------- gate ----------
__global__ void gate_kernel(const float* __restrict__ ent_rows,
                            const float* __restrict__ g1w, const float* __restrict__ g1b,
                            const float* __restrict__ g2w, const float* __restrict__ g2b,
                            int* __restrict__ keep) {
    int bh = blockIdx.x;
    int tid = threadIdx.x;
    __shared__ float red[4];
    float ls = 0.f;
    for (int j = tid; j < NN; j += 256) ls += ent_rows[bh * NN + j];
    for (int o = 32; o > 0; o >>= 1) ls += __shfl_down(ls, o);
    int lane = tid & 63, wid = tid >> 6;
    if (lane == 0) red[wid] = ls;
    __syncthreads();
    if (tid == 0) {
        float ent = (red[0] + red[1] + red[2] + red[3]) / (float)NN;
        float val = g2b[0];
#pragma unroll
        for (int j = 0; j < 16; j++) {
            float hid = ent * g1w[j] + g1b[j];
            if (hid < 0.f) hid = 0.f;
            val += hid * g2w[j];
        }
        float ratio = 0.9f / (1.f + expf(-val)) + 0.1f;
        int kp = (int)ceilf(ratio * (float)NN);
        if (kp < 1) kp = 1;
        if (kp > NN) kp = NN;
        keep[bh] = kp;
    }
}

// ---------- phase 2: RTS2, f4 K/V loads, ping-pong register prefetch ----------

// one QK^T tile step: prefetch next K tile into NXT while doing FMAs with CUR
#define QKT_STEP(KT, CUR, NXT)                                                 \
    {                                                                          \
        int ktn = ((KT) + 1 < 25) ? (KT) + 1 : 24;                             \
        const f4* kq = (const f4*)(ktb + ktn * TSTR + lane * 32);              \
        _Pragma("unroll")                                                      \
        for (int i = 0; i < 8; i++) NXT[i] = kq[i];                            \
        float a0 = 0.f, a1 = 0.f;                                              \
        _Pragma("unroll")                                                      \
        for (int i = 0; i < 8; i++) {                                          \
            _Pragma("unroll")                                                  \
            for (int c = 0; c < 4; c++) {                                      \
                float kv = CUR[i][c];                                          \
                a0 += q0[i * 4 + c] * kv;                                      \
                a1 += q1[i * 4 + c] * kv;                                      \
            }                                                                  \
        }                                                                      \
        a0 *= SCALE; a1 *= SCALE;                                              \
        int j = (KT) * 64 + lane;                                              \
        att[0][j] = a0; att[1][j] = a1;                                        \
        m0 = fmaxf(m0, a0); m1 = fmaxf(m1, a1);                                \
    }

// one PV tile step: prefetch next V tile into NXT while doing FMAs with CUR
#define PV_STEP(KT, CUR, NXT)                                                  \
    {                                                                          \
        int ktn = ((KT) + 1 < 25) ? (KT) + 1 : 24;                             \
        const f4* vq = (const f4*)(vtb + ktn * TSTR + lane * 32);              \
        _Pragma("unroll")                                                      \
        for (int i = 0; i < 8; i++) NXT[i] = vq[i];                            \
        int j = (KT) * 64 + lane;                                              \
        float a0 = att[0][j], a1 = att[1][j];                                  \
        float p0 = (a0 >= kth0) ? __expf(a0 - m0) : 0.f;                       \
        float p1 = (a1 >= kth1) ? __expf(a1 - m1) : 0.f;                       \
        S0 += p0; S1 += p1;                                                    \
        _Pragma("unroll")                                                      \
        for (int i = 0; i < 8; i++) {                                          \
            _Pragma("unroll")                                                  \
            for (int c = 0; c < 4; c++) {                                      \
                float vv = CUR[i][c];                                          \
                acc0[i * 4 + c] += p0 * vv;                                    \
                acc1[i * 4 + c] += p1 * vv;                                    \
            }                                                                  \
        }                                                                      \
    }

__global__ __launch_bounds__(64) void sparse_attn_kernel(const float* __restrict__ qkv_t,
                                                         const int* __restrict__ keep,
                                                         float* __restrict__ oht) {
    int blk = blockIdx.x;
    int rt = blk % (NN / RTS);
    int bh = blk / (NN / RTS);
    int h = bh % NHEADS, b = bh / NHEADS;
    int row0 = rt * RTS;
    __shared__ float att[RTS][NN];       // 12.8 KB
    __shared__ unsigned hist[RTS][256];  // 2 KB
    __shared__ float Qs[RTS][HD];        // 0.25 KB
    int tid = threadIdx.x;               // 0..63, one wave
    const float* qt = qkv_t + ((size_t)(b * 3 + 0) * NHEADS + h) * HSTR;
    const float* ktb = qkv_t + ((size_t)(b * 3 + 1) * NHEADS + h) * HSTR;
    const float* vtb = qkv_t + ((size_t)(b * 3 + 2) * NHEADS + h) * HSTR;
    {
        int r = tid >> 5, d = tid & 31;
        int row = row0 + r;
        Qs[r][d] = qt[(row >> 6) * TSTR + (row & 63) * 32 + d];
    }
    int want = keep[bh];
    __syncthreads();
    int lane = tid;
    float q0[HD], q1[HD];
#pragma unroll
    for (int d = 0; d < HD; d++) { q0[d] = Qs[0][d]; q1[d] = Qs[1][d]; }

    // ---- QK^T into LDS att rows; track per-row max; ping-pong K prefetch ----
    float m0 = -1e30f, m1 = -1e30f;
    f4 kcA[8], kcB[8];
    {
        const f4* kp0 = (const f4*)(ktb + lane * 32);
#pragma unroll
        for (int i = 0; i < 8; i++) kcA[i] = kp0[i];
    }
#pragma unroll 1
    for (int kt = 0; kt < 24; kt += 2) {
        QKT_STEP(kt, kcA, kcB);
        QKT_STEP(kt + 1, kcB, kcA);
    }
    QKT_STEP(24, kcA, kcB);
#pragma unroll
    for (int off = 1; off < 64; off <<= 1) {
        m0 = fmaxf(m0, __shfl_xor(m0, off));
        m1 = fmaxf(m1, __shfl_xor(m1, off));
    }

    // ---- cache monotone keys in registers (32 lanes per row; rows in half-waves) ----
    int l = lane & 31;
    int r = (lane < 32) ? 0 : 1;
    unsigned kvr[50];
#pragma unroll
    for (int k2 = 0; k2 < 50; k2++) kvr[k2] = fkey(att[r][k2 * 32 + l]);

    // ---- radix select kth-largest from register keys (r8-proven) ----
    unsigned prefixHigh = 0;
    for (int pass = 0; pass < 4; pass++) {
        int shift = 24 - 8 * pass;
#pragma unroll
        for (int i = 0; i < 8; i++) hist[r][248 - 8 * l + i] = 0u;
#pragma unroll
        for (int k2 = 0; k2 < 50; k2++) {
            unsigned u = kvr[k2];
            bool ok = (pass == 0) || ((u >> (shift + 8)) == prefixHigh);
            if (ok) atomicAdd(&hist[r][(u >> shift) & 255u], 1u);
        }
        unsigned sch = 0;
#pragma unroll
        for (int i = 0; i < 8; i++) sch += hist[r][248 - 8 * l + i];
        unsigned inc = sch;
#pragma unroll
        for (int dlt = 1; dlt < 32; dlt <<= 1) {
            unsigned tv = __shfl_up(inc, dlt, 32);
            if (l >= dlt) inc += tv;
        }
        unsigned pref = inc - sch;
        bool found = (pref < (unsigned)want) && ((unsigned)want <= inc);
        int bsel = -1, wnew = 0;
        if (found) {
            unsigned want2 = (unsigned)want - pref, cum = 0;
#pragma unroll
            for (int i = 0; i < 8; i++) {
                int bbin = 255 - 8 * l - i;
                unsigned c = hist[r][bbin];
                if (bsel < 0 && cum + c >= want2) { bsel = bbin; wnew = (int)(want2 - cum); }
                cum += c;
            }
        }
        unsigned long long mk = __ballot(found);
        int src = (lane < 32) ? __builtin_ctzll(mk & 0xffffffffULL)
                              : __builtin_ctzll(mk >> 32) + 32;
        bsel = __shfl(bsel, src);
        want = __shfl(wnew, src);
        prefixHigh = (prefixHigh << 8) | (unsigned)bsel;
    }
    float kth = finv(prefixHigh);
    float kth0 = __shfl(kth, 0);
    float kth1 = __shfl(kth, 32);

    // ---- fused sparse softmax + PV (S accumulated inline); ping-pong V prefetch ----
    float acc0[HD], acc1[HD];
#pragma unroll
    for (int d = 0; d < HD; d++) { acc0[d] = 0.f; acc1[d] = 0.f; }
    float S0 = 0.f, S1 = 0.f;
    f4 vcA[8], vcB[8];
    {
        const f4* vp0 = (const f4*)(vtb + lane * 32);
#pragma unroll
        for (int i = 0; i < 8; i++) vcA[i] = vp0[i];
    }
#pragma unroll 1
    for (int kt = 0; kt < 24; kt += 2) {
        PV_STEP(kt, vcA, vcB);
        PV_STEP(kt + 1, vcB, vcA);
    }
    PV_STEP(24, vcA, vcB);
#pragma unroll
    for (int off = 1; off < 64; off <<= 1) {
        S0 += __shfl_xor(S0, off);
        S1 += __shfl_xor(S1, off);
    }

    // ---- reduce acc over the 64 lanes via LDS scratch (reuses att rows) ----
    float* scratch = &att[0][0];  // 3200 floats; need 64*33=2112
    int dd = lane & 31;
    int jb = (lane < 32) ? 0 : 32;
#pragma unroll
    for (int d = 0; d < HD; d++) scratch[lane * 33 + d] = acc0[d];
    float sum0 = 0.f;
#pragma unroll
    for (int jj = 0; jj < 32; jj++) sum0 += scratch[(jb + jj) * 33 + dd];
    sum0 += __shfl_xor(sum0, 32);
#pragma unroll
    for (int d = 0; d < HD; d++) scratch[lane * 33 + d] = acc1[d];
    float sum1 = 0.f;
#pragma unroll
    for (int jj = 0; jj < 32; jj++) sum1 += scratch[(jb + jj) * 33 + dd];
    sum1 += __shfl_xor(sum1, 32);

    if (lane < 32) {
        size_t base = ((size_t)b * CDIM + h * HD + dd) * NN + row0;
        oht[base + 0] = sum0 / S0;
        oht[base + 1] = sum1 / S1;
    }
}

// ---------- output projection from oht [b][c][n]: 8 oc per thread ----------
__global__ __launch_bounds__(256) void proj_kernel(const float* __restrict__ oht,
                                                   const float* __restrict__ pw,
                                                   const float* __restrict__ pb,
                                                   float* __restrict__ out) {
    int blk = blockIdx.x;
    int st = blk % 7;
    int t2 = blk / 7;
    int ocg = t2 % (CDIM / 8);
    int b = t2 / (CDIM / 8);
    int s = st * 256 + threadIdx.x;
    if (s >= NN) return;
    int co0 = ocg * 8;
    const float* ib = oht + (size_t)b * CDIM * NN + s;
    const float* w0 = pw + (size_t)co0 * CDIM;
    float a[8];
#pragma unroll
    for (int i = 0; i < 8; i++) a[i] = pb[co0 + i];
#pragma unroll 4
    for (int c = 0; c < CDIM; c++) {
        float xv = ib[(size_t)c * NN];
#pragma unroll
        for (int i = 0; i < 8; i++) a[i] += w0[i * CDIM + c] * xv;
    }
    float* ob = out + ((size_t)b * CDIM + co0) * NN + s;
#pragma unroll
    for (int i = 0; i < 8; i++) ob[(size_t)i * NN] = a[i];
}

extern "C" void kernel_launch(void* const* d_in, const int* in_sizes, int n_in,
                              void* d_out, int out_size, void* d_ws, size_t ws_size,
                              hipStream_t stream) {
    const float* x      = (const float*)d_in[0];
    const float* qkv_w  = (const float*)d_in[1];
    const float* qkv_b  = (const float*)d_in[2];
    const float* pos_w  = (const float*)d_in[3];
    const float* pos_b  = (const float*)d_in[4];
    const float* proj_w = (const float*)d_in[5];
    const float* proj_b = (const float*)d_in[6];
    const float* g1w    = (const float*)d_in[7];
    const float* g1b    = (const float*)d_in[8];
    const float* g2w    = (const float*)d_in[9];
    const float* g2b    = (const float*)d_in[10];
    float* out = (float*)d_out;

    float* ws   = (float*)d_ws;
    float* buf1 = ws;                                  // BB*C3*NN  ([b][c][s])
    float* buf2 = buf1 + (size_t)BB * C3 * NN;         // BB*C3*NN  (j-tiled [kt][j][d])
    float* ent  = buf2 + (size_t)BB * C3 * NN;         // BB*NHEADS*NN
    float* oht  = ent + (size_t)BB * NHEADS * NN;      // BB*CDIM*NN  ([b][c][n])
    int* keep   = (int*)(oht + (size_t)BB * CDIM * NN);

    conv1x1_kernel<<<BB * (C3 / 8) * 7, 256, 0, stream>>>(x, qkv_w, qkv_b, buf1);
    dwconv_kernel<<<BB * C3 * NN / 256, 256, 0, stream>>>(buf1, pos_w, pos_b, buf2);
    entropy_kernel<<<NHEADS * BB * (NN / RTE), 256, 0, stream>>>(buf2, ent);
    gate_kernel<<<BB * NHEADS, 256, 0, stream>>>(ent, g1w, g1b, g2w, g2b, keep);
    sparse_attn_kernel<<<NHEADS * BB * (NN / RTS), 64, 0, stream>>>(buf2, keep, oht);
    proj_kernel<<<BB * (CDIM / 8) * 7, 256, 0, stream>>>(oht, proj_w, proj_b, out);
}

// Round 4
// 457.353 us; speedup vs baseline: 2.2461x; 2.2461x over previous
//
#include <hip/hip_runtime.h>
#include <math.h>

#define BB 2
#define CDIM 256
#define NHEADS 8
#define HD 32
#define HH 40
#define WW 40
#define NN 1600
#define C3 768
#define SCALE 0.17677669529663687f  // 1/sqrt(32)
#define RTE 8            // rows per block, entropy kernel (2 per wave)
#define RTS 2            // rows per block, sparse kernel (2 waves, tile-split)
#define TSTR 2048        // tile stride: 32 d * 64 jl  (layout [kt][d][j], j contiguous)
#define HSTR 51200       // per (b,part,h): 25 tiles * 2048

// ---------- helpers ----------
__device__ inline unsigned fkey(float f) {
    unsigned u = __float_as_uint(f);
    return (u & 0x80000000u) ? ~u : (u | 0x80000000u);
}
__device__ inline float finv(unsigned u) {
    unsigned v = (u & 0x80000000u) ? (u ^ 0x80000000u) : ~u;
    return __uint_as_float(v);
}

// ---------- 1x1 conv: 8 output channels per thread ----------
__global__ __launch_bounds__(256) void conv1x1_kernel(const float* __restrict__ x,
                                                      const float* __restrict__ w,
                                                      const float* __restrict__ bias,
                                                      float* __restrict__ out) {
    int blk = blockIdx.x;
    int st = blk % 7;
    int t2 = blk / 7;
    int ocg = t2 % (C3 / 8);
    int b = t2 / (C3 / 8);
    int s = st * 256 + threadIdx.x;
    if (s >= NN) return;
    int oc0 = ocg * 8;
    const float* xb = x + (size_t)b * CDIM * NN + s;
    const float* w0 = w + (size_t)oc0 * CDIM;
    float a[8];
#pragma unroll
    for (int i = 0; i < 8; i++) a[i] = bias[oc0 + i];
#pragma unroll 4
    for (int ic = 0; ic < CDIM; ic++) {
        float xv = xb[(size_t)ic * NN];
#pragma unroll
        for (int i = 0; i < 8; i++) a[i] += w0[i * CDIM + ic] * xv;
    }
    float* ob = out + ((size_t)b * C3 + oc0) * NN + s;
#pragma unroll
    for (int i = 0; i < 8; i++) ob[(size_t)i * NN] = a[i];
}

// ---------- depthwise 3x3 pad1; writes j-tiled layout [b][part][h][kt][d][jl] ----------
__global__ __launch_bounds__(256) void dwconv_kernel(const float* __restrict__ in,
                                                     const float* __restrict__ w,
                                                     const float* __restrict__ bias,
                                                     float* __restrict__ out_t) {
    int idx = blockIdx.x * 256 + threadIdx.x;
    int s = idx % NN;
    int t = idx / NN;
    int c = t % C3;
    int b = t / C3;
    int y = s / WW, xx = s % WW;
    const float* ib = in + ((size_t)b * C3 + c) * NN;
    const float* wr = w + (size_t)c * 9;
    float acc = bias[c];
#pragma unroll
    for (int ky = 0; ky < 3; ky++) {
        int iy = y + ky - 1;
        if (iy < 0 || iy >= HH) continue;
#pragma unroll
        for (int kx = 0; kx < 3; kx++) {
            int ix = xx + kx - 1;
            if (ix < 0 || ix >= WW) continue;
            acc += wr[ky * 3 + kx] * ib[iy * WW + ix];
        }
    }
    int part = c >> 8;
    int r = c & 255;
    int hh = r >> 5;
    int d = r & 31;
    out_t[((size_t)(b * 3 + part) * NHEADS + hh) * HSTR + (s >> 6) * TSTR + d * 64 + (s & 63)] = acc;
}

// ---------- phase 1: streaming entropy on tiled layout (r8 structure) ----------
__global__ __launch_bounds__(256) void entropy_kernel(const float* __restrict__ qkv_t,
                                                      float* __restrict__ ent) {
    int blk = blockIdx.x;      // bh*(NN/RTE) + rt
    int rt = blk % (NN / RTE);
    int bh = blk / (NN / RTE);
    int h = bh % NHEADS, b = bh / NHEADS;
    int row0 = rt * RTE;
    __shared__ float Qs[RTE][HD];
    int tid = threadIdx.x;
    const float* qt = qkv_t + ((size_t)(b * 3 + 0) * NHEADS + h) * HSTR;
    const float* ktb = qkv_t + ((size_t)(b * 3 + 1) * NHEADS + h) * HSTR;
    {
        int r = tid >> 5, d = tid & 31;
        int row = row0 + r;
        Qs[r][d] = qt[(row >> 6) * TSTR + d * 64 + (row & 63)];
    }
    __syncthreads();
    int w = tid >> 6, lane = tid & 63;
    int lr0 = 2 * w, lr1 = lr0 + 1;
    float q0[HD], q1[HD];
#pragma unroll
    for (int d = 0; d < HD; d++) { q0[d] = Qs[lr0][d]; q1[d] = Qs[lr1][d]; }
    float S0 = 0.f, T0 = 0.f, S1 = 0.f, T1 = 0.f;
#pragma unroll 1
    for (int kt = 0; kt < 25; kt++) {
        const float* kp = ktb + kt * TSTR + lane;
        float a0 = 0.f, a1 = 0.f;
#pragma unroll
        for (int dc = 0; dc < 4; dc++) {
            float kc[8];
#pragma unroll
            for (int i = 0; i < 8; i++) kc[i] = kp[(dc * 8 + i) * 64];
#pragma unroll
            for (int i = 0; i < 8; i++) {
                a0 += q0[dc * 8 + i] * kc[i];
                a1 += q1[dc * 8 + i] * kc[i];
            }
        }
        a0 *= SCALE; a1 *= SCALE;
        float e0 = __expf(a0), e1 = __expf(a1);
        S0 += e0; T0 += e0 * a0;
        S1 += e1; T1 += e1 * a1;
    }
#pragma unroll
    for (int o = 1; o < 64; o <<= 1) {
        S0 += __shfl_xor(S0, o); T0 += __shfl_xor(T0, o);
        S1 += __shfl_xor(S1, o); T1 += __shfl_xor(T1, o);
    }
    if (lane == 0) {
        ent[(size_t)bh * NN + row0 + lr0] = logf(S0) - T0 / S0;
        ent[(size_t)bh * NN + row0 + lr1] = logf(S1) - T1 / S1;
    }
}

// ---------- gate ----------
__global__ void gate_kernel(const float* __restrict__ ent_rows,
                            const float* __restrict__ g1w, const float* __restrict__ g1b,
                            const float* __restrict__ g2w, const float* __restrict__ g2b,
                            int* __restrict__ keep) {
    int bh = blockIdx.x;
    int tid = threadIdx.x;
    __shared__ float red[4];
    float ls = 0.f;
    for (int j = tid; j < NN; j += 256) ls += ent_rows[bh * NN + j];
    for (int o = 32; o > 0; o >>= 1) ls += __shfl_down(ls, o);
    int lane = tid & 63, wid = tid >> 6;
    if (lane == 0) red[wid] = ls;
    __syncthreads();
    if (tid == 0) {
        float ent = (red[0] + red[1] + red[2] + red[3]) / (float)NN;
        float val = g2b[0];
#pragma unroll
        for (int j = 0; j < 16; j++) {
            float hid = ent * g1w[j] + g1b[j];
            if (hid < 0.f) hid = 0.f;
            val += hid * g2w[j];
        }
        float ratio = 0.9f / (1.f + expf(-val)) + 0.1f;
        int kp = (int)ceilf(ratio * (float)NN);
        if (kp < 1) kp = 1;
        if (kp > NN) kp = NN;
        keep[bh] = kp;
    }
}

// ---------- phase 2: 2 rows, 2 waves per block (tile-split), wave-per-row select ----------
__global__ __launch_bounds__(128) void sparse_attn_kernel(const float* __restrict__ qkv_t,
                                                          const int* __restrict__ keep,
                                                          float* __restrict__ oht) {
    int blk = blockIdx.x;
    int rt = blk % (NN / RTS);
    int bh = blk / (NN / RTS);
    int h = bh % NHEADS, b = bh / NHEADS;
    int row0 = rt * RTS;
    __shared__ float att[RTS][NN];       // 12.8 KB (reused as reduce scratch at the end)
    __shared__ unsigned hist[RTS][256];  // 2 KB
    __shared__ float Qs[RTS][HD];        // 0.25 KB
    __shared__ float red[RTS][2];        // per-wave partial max, then partial S
    __shared__ float kthS[RTS];          // kth broadcast
    int tid = threadIdx.x;               // 0..127, two waves
    int wv = tid >> 6;                   // wave id 0/1
    int lane = tid & 63;
    const float* qt = qkv_t + ((size_t)(b * 3 + 0) * NHEADS + h) * HSTR;
    const float* ktb = qkv_t + ((size_t)(b * 3 + 1) * NHEADS + h) * HSTR;
    const float* vtb = qkv_t + ((size_t)(b * 3 + 2) * NHEADS + h) * HSTR;
    if (tid < 64) {
        int r = tid >> 5, d = tid & 31;
        int row = row0 + r;
        Qs[r][d] = qt[(row >> 6) * TSTR + d * 64 + (row & 63)];
    }
    int want = keep[bh];
    __syncthreads();
    float q0[HD], q1[HD];
#pragma unroll
    for (int d = 0; d < HD; d++) { q0[d] = Qs[0][d]; q1[d] = Qs[1][d]; }

    // tile split: wave 0 -> tiles [0,13), wave 1 -> [13,25)
    int t0 = wv ? 13 : 0;
    int t1 = wv ? 25 : 13;

    // ---- QK^T into LDS att rows; per-wave partial max ----
    float m0 = -1e30f, m1 = -1e30f;
#pragma unroll 1
    for (int kt = t0; kt < t1; kt++) {
        const float* kp = ktb + kt * TSTR + lane;
        float a0 = 0.f, a1 = 0.f;
#pragma unroll
        for (int dc = 0; dc < 4; dc++) {
            float kc[8];
#pragma unroll
            for (int i = 0; i < 8; i++) kc[i] = kp[(dc * 8 + i) * 64];
#pragma unroll
            for (int i = 0; i < 8; i++) {
                a0 += q0[dc * 8 + i] * kc[i];
                a1 += q1[dc * 8 + i] * kc[i];
            }
        }
        a0 *= SCALE; a1 *= SCALE;
        int j = kt * 64 + lane;
        att[0][j] = a0;
        att[1][j] = a1;
        m0 = fmaxf(m0, a0); m1 = fmaxf(m1, a1);
    }
#pragma unroll
    for (int off = 1; off < 64; off <<= 1) {
        m0 = fmaxf(m0, __shfl_xor(m0, off));
        m1 = fmaxf(m1, __shfl_xor(m1, off));
    }
    if (lane == 0) { red[0][wv] = m0; red[1][wv] = m1; }
    __syncthreads();
    m0 = fmaxf(red[0][0], red[0][1]);
    m1 = fmaxf(red[1][0], red[1][1]);

    // ---- radix select: wave wv selects kth-largest for row wv (64 lanes, 25 keys, 4 bins) ----
    {
        int r = wv;
        unsigned kvr[25];
#pragma unroll
        for (int k2 = 0; k2 < 25; k2++) kvr[k2] = fkey(att[r][k2 * 64 + lane]);
        unsigned prefixHigh = 0;
        for (int pass = 0; pass < 4; pass++) {
            int shift = 24 - 8 * pass;
#pragma unroll
            for (int i = 0; i < 4; i++) hist[r][252 - 4 * lane + i] = 0u;
#pragma unroll
            for (int k2 = 0; k2 < 25; k2++) {
                unsigned u = kvr[k2];
                bool ok = (pass == 0) || ((u >> (shift + 8)) == prefixHigh);
                if (ok) atomicAdd(&hist[r][(u >> shift) & 255u], 1u);
            }
            unsigned sch = 0;
#pragma unroll
            for (int i = 0; i < 4; i++) sch += hist[r][252 - 4 * lane + i];
            unsigned inc = sch;
#pragma unroll
            for (int dlt = 1; dlt < 64; dlt <<= 1) {
                unsigned tv = __shfl_up(inc, dlt, 64);
                if (lane >= dlt) inc += tv;
            }
            unsigned pref = inc - sch;
            bool found = (pref < (unsigned)want) && ((unsigned)want <= inc);
            int bsel = -1, wnew = 0;
            if (found) {
                unsigned want2 = (unsigned)want - pref, cum = 0;
#pragma unroll
                for (int i = 0; i < 4; i++) {
                    int bbin = 255 - 4 * lane - i;
                    unsigned c = hist[r][bbin];
                    if (bsel < 0 && cum + c >= want2) { bsel = bbin; wnew = (int)(want2 - cum); }
                    cum += c;
                }
            }
            unsigned long long mk = __ballot(found);
            int src = __builtin_ctzll(mk);
            bsel = __shfl(bsel, src);
            want = __shfl(wnew, src);
            prefixHigh = (prefixHigh << 8) | (unsigned)bsel;
        }
        if (lane == 0) kthS[r] = finv(prefixHigh);
    }
    __syncthreads();
    float kth0 = kthS[0];
    float kth1 = kthS[1];

    // ---- fused sparse softmax + PV over this wave's tiles ----
    float acc0[HD], acc1[HD];
#pragma unroll
    for (int d = 0; d < HD; d++) { acc0[d] = 0.f; acc1[d] = 0.f; }
    float S0 = 0.f, S1 = 0.f;
#pragma unroll 1
    for (int kt = t0; kt < t1; kt++) {
        const float* vp = vtb + kt * TSTR + lane;
        int j = kt * 64 + lane;
        float a0 = att[0][j];
        float a1 = att[1][j];
        float p0 = (a0 >= kth0) ? __expf(a0 - m0) : 0.f;
        float p1 = (a1 >= kth1) ? __expf(a1 - m1) : 0.f;
        S0 += p0; S1 += p1;
#pragma unroll
        for (int d = 0; d < HD; d++) {
            float vv = vp[d * 64];
            acc0[d] += p0 * vv;
            acc1[d] += p1 * vv;
        }
    }
#pragma unroll
    for (int off = 1; off < 64; off <<= 1) {
        S0 += __shfl_xor(S0, off);
        S1 += __shfl_xor(S1, off);
    }
    if (lane == 0) { red[0][wv] = S0; red[1][wv] = S1; }

    // ---- fold acc 64 -> 16 lanes in-register, then cross-wave combine via LDS ----
#pragma unroll
    for (int d = 0; d < HD; d++) {
        acc0[d] += __shfl_xor(acc0[d], 32);
        acc1[d] += __shfl_xor(acc1[d], 32);
        acc0[d] += __shfl_xor(acc0[d], 16);
        acc1[d] += __shfl_xor(acc1[d], 16);
    }
    __syncthreads();                      // all att reads + red writes done
    float* sc = &att[0][0];               // reuse: need (wv*2+rowsel)*16+idx < 64 rows * 33 = 2112 floats
    {
        int idx = lane & 15;
        if (lane < 16) {
#pragma unroll
            for (int d = 0; d < HD; d++) sc[((wv * 2 + 0) * 16 + idx) * 33 + d] = acc0[d];
        } else if (lane < 32) {
#pragma unroll
            for (int d = 0; d < HD; d++) sc[((wv * 2 + 1) * 16 + idx) * 33 + d] = acc1[d];
        }
    }
    __syncthreads();
    if (wv == 0) {
        int row = lane >> 5;              // 0/1
        int d = lane & 31;
        float s = 0.f;
#pragma unroll
        for (int w2 = 0; w2 < 2; w2++)
#pragma unroll
            for (int i = 0; i < 16; i++)
                s += sc[((w2 * 2 + row) * 16 + i) * 33 + d];
        float Srow = red[row][0] + red[row][1];
        oht[((size_t)b * CDIM + h * HD + d) * NN + row0 + row] = s / Srow;
    }
}

// ---------- output projection from oht [b][c][n]: 8 oc per thread ----------
__global__ __launch_bounds__(256) void proj_kernel(const float* __restrict__ oht,
                                                   const float* __restrict__ pw,
                                                   const float* __restrict__ pb,
                                                   float* __restrict__ out) {
    int blk = blockIdx.x;
    int st = blk % 7;
    int t2 = blk / 7;
    int ocg = t2 % (CDIM / 8);
    int b = t2 / (CDIM / 8);
    int s = st * 256 + threadIdx.x;
    if (s >= NN) return;
    int co0 = ocg * 8;
    const float* ib = oht + (size_t)b * CDIM * NN + s;
    const float* w0 = pw + (size_t)co0 * CDIM;
    float a[8];
#pragma unroll
    for (int i = 0; i < 8; i++) a[i] = pb[co0 + i];
#pragma unroll 4
    for (int c = 0; c < CDIM; c++) {
        float xv = ib[(size_t)c * NN];
#pragma unroll
        for (int i = 0; i < 8; i++) a[i] += w0[i * CDIM + c] * xv;
    }
    float* ob = out + ((size_t)b * CDIM + co0) * NN + s;
#pragma unroll
    for (int i = 0; i < 8; i++) ob[(size_t)i * NN] = a[i];
}

extern "C" void kernel_launch(void* const* d_in, const int* in_sizes, int n_in,
                              void* d_out, int out_size, void* d_ws, size_t ws_size,
                              hipStream_t stream) {
    const float* x      = (const float*)d_in[0];
    const float* qkv_w  = (const float*)d_in[1];
    const float* qkv_b  = (const float*)d_in[2];
    const float* pos_w  = (const float*)d_in[3];
    const float* pos_b  = (const float*)d_in[4];
    const float* proj_w = (const float*)d_in[5];
    const float* proj_b = (const float*)d_in[6];
    const float* g1w    = (const float*)d_in[7];
    const float* g1b    = (const float*)d_in[8];
    const float* g2w    = (const float*)d_in[9];
    const float* g2b    = (const float*)d_in[10];
    float* out = (float*)d_out;

    float* ws   = (float*)d_ws;
    float* buf1 = ws;                                  // BB*C3*NN  ([b][c][s])
    float* buf2 = buf1 + (size_t)BB * C3 * NN;         // BB*C3*NN  (j-tiled [kt][d][j])
    float* ent  = buf2 + (size_t)BB * C3 * NN;         // BB*NHEADS*NN
    float* oht  = ent + (size_t)BB * NHEADS * NN;      // BB*CDIM*NN  ([b][c][n])
    int* keep   = (int*)(oht + (size_t)BB * CDIM * NN);

    conv1x1_kernel<<<BB * (C3 / 8) * 7, 256, 0, stream>>>(x, qkv_w, qkv_b, buf1);
    dwconv_kernel<<<BB * C3 * NN / 256, 256, 0, stream>>>(buf1, pos_w, pos_b, buf2);
    entropy_kernel<<<NHEADS * BB * (NN / RTE), 256, 0, stream>>>(buf2, ent);
    gate_kernel<<<BB * NHEADS, 256, 0, stream>>>(ent, g1w, g1b, g2w, g2b, keep);
    sparse_attn_kernel<<<NHEADS * BB * (NN / RTS), 128, 0, stream>>>(buf2, keep, oht);
    proj_kernel<<<BB * (CDIM / 8) * 7, 256, 0, stream>>>(oht, proj_w, proj_b, out);
}